// Round 1
// baseline (2033.154 us; speedup 1.0000x reference)
//
#include <hip/hip_runtime.h>

typedef _Float16 f16;
typedef _Float16 f16x8 __attribute__((ext_vector_type(8)));
typedef _Float16 f16x4 __attribute__((ext_vector_type(4)));
typedef float f32x4 __attribute__((ext_vector_type(4)));

// ---------------------------------------------------------------------------
// async 16B global -> LDS copy (global_load_lds_dwordx4)
// NOTE: LDS dest is wave-uniform base + lane*16; our layouts respect that.
// ---------------------------------------------------------------------------
__device__ __forceinline__ void gload_lds16(const void* g, void* l) {
  __builtin_amdgcn_global_load_lds(
      (const __attribute__((address_space(1))) unsigned int*)g,
      (__attribute__((address_space(3))) unsigned int*)l,
      16, 0, 0);
}

// ---------------------------------------------------------------------------
// C = scale * A * B^T  (A: M x K row-major, B: N x K row-major, C: M x N)
// m97 structure: 128x128 tile, BK=32, 256 thr = 4 waves in 2x2, each wave
// 64x64 via 4x4 grid of 16x16x32 f16 MFMAs. All dims multiples of 128/32.
// z-batched via sAz/sBz/sCz element strides.
// ---------------------------------------------------------------------------
template <typename CT>
__global__ __launch_bounds__(256) void gemm_bt(
    const f16* __restrict__ A, const f16* __restrict__ B, CT* __restrict__ C,
    int K, int lda, int ldb, int ldc,
    long long sAz, long long sBz, long long sCz, float scale)
{
  __shared__ f16 As[128 * 32];  // [m][k] row-major, 8 KiB
  __shared__ f16 Bs[128 * 32];  // [n][k] row-major

  const int t    = threadIdx.x;
  const int lane = t & 63;
  const int wave = t >> 6;
  const int wm   = wave >> 1;   // 0..1
  const int wn   = wave & 1;    // 0..1

  const long long bm = (long long)blockIdx.y * 128;
  const long long bn = (long long)blockIdx.x * 128;

  const f16* Ab = A + (long long)blockIdx.z * sAz;
  const f16* Bb = B + (long long)blockIdx.z * sBz;
  CT*        Cb = C + (long long)blockIdx.z * sCz;

  // staging: 128x32 f16 tile = 512 chunks of 16B; thread t does chunks t, t+256
  const int row0 = t >> 2;        // 0..63
  const int kp   = (t & 3) * 8;   // 0,8,16,24
  const f16* ag0 = Ab + (bm + row0)      * lda + kp;
  const f16* ag1 = Ab + (bm + row0 + 64) * lda + kp;
  const f16* bg0 = Bb + (bn + row0)      * ldb + kp;
  const f16* bg1 = Bb + (bn + row0 + 64) * ldb + kp;
  f16* al0 = As + t * 8;
  f16* al1 = As + (t + 256) * 8;
  f16* bl0 = Bs + t * 8;
  f16* bl1 = Bs + (t + 256) * 8;

  f32x4 acc[4][4];
  #pragma unroll
  for (int i = 0; i < 4; ++i)
    #pragma unroll
    for (int j = 0; j < 4; ++j)
      acc[i][j] = {0.f, 0.f, 0.f, 0.f};

  // fragment addressing: A[m=lane&15][k=(lane>>4)*8+j], B^T[k][n=lane&15]
  const int ar = wm * 64 + (lane & 15);
  const int br = wn * 64 + (lane & 15);
  const int lk = (lane >> 4) * 8;

  for (int k0 = 0; k0 < K; k0 += 32) {
    __syncthreads();               // previous tile's frag reads done
    gload_lds16(ag0 + k0, al0);
    gload_lds16(ag1 + k0, al1);
    gload_lds16(bg0 + k0, bl0);
    gload_lds16(bg1 + k0, bl1);
    __syncthreads();               // drains vmcnt -> staging complete

    f16x8 af[4], bf[4];
    #pragma unroll
    for (int mi = 0; mi < 4; ++mi)
      af[mi] = *(const f16x8*)&As[(ar + mi * 16) * 32 + lk];
    #pragma unroll
    for (int ni = 0; ni < 4; ++ni)
      bf[ni] = *(const f16x8*)&Bs[(br + ni * 16) * 32 + lk];

    #pragma unroll
    for (int mi = 0; mi < 4; ++mi)
      #pragma unroll
      for (int ni = 0; ni < 4; ++ni)
        acc[mi][ni] = __builtin_amdgcn_mfma_f32_16x16x32_f16(
            af[mi], bf[ni], acc[mi][ni], 0, 0, 0);
  }

  // epilogue: D row = (lane>>4)*4 + r, col = lane&15  (verified m89/m91)
  const long long crow = bm + wm * 64 + (lane >> 4) * 4;
  const long long ccol = bn + wn * 64 + (lane & 15);
  #pragma unroll
  for (int mi = 0; mi < 4; ++mi)
    #pragma unroll
    for (int ni = 0; ni < 4; ++ni)
      #pragma unroll
      for (int r = 0; r < 4; ++r)
        Cb[(crow + mi * 16 + r) * ldc + ccol + ni * 16] =
            (CT)(acc[mi][ni][r] * scale);
}

// ---------------------------------------------------------------------------
// row softmax: S (fp32, row of T=4096) -> P (f16). One 256-thr block per row.
// ---------------------------------------------------------------------------
__global__ __launch_bounds__(256) void softmax_rows(
    const float* __restrict__ S, f16* __restrict__ P, int T)
{
  const int row = blockIdx.x;
  const int t   = threadIdx.x;
  const float* s = S + (size_t)row * T;
  f16*         p = P + (size_t)row * T;

  float4 v[4];
  float mx = -3.4e38f;
  #pragma unroll
  for (int i = 0; i < 4; ++i) {
    v[i] = *(const float4*)(s + i * 1024 + t * 4);
    mx = fmaxf(mx, fmaxf(fmaxf(v[i].x, v[i].y), fmaxf(v[i].z, v[i].w)));
  }
  __shared__ float red[4];
  #pragma unroll
  for (int o = 32; o > 0; o >>= 1) mx = fmaxf(mx, __shfl_xor(mx, o, 64));
  if ((t & 63) == 0) red[t >> 6] = mx;
  __syncthreads();
  mx = fmaxf(fmaxf(red[0], red[1]), fmaxf(red[2], red[3]));
  __syncthreads();                         // protect red reuse

  float sum = 0.f;
  #pragma unroll
  for (int i = 0; i < 4; ++i) {
    v[i].x = __expf(v[i].x - mx);
    v[i].y = __expf(v[i].y - mx);
    v[i].z = __expf(v[i].z - mx);
    v[i].w = __expf(v[i].w - mx);
    sum += (v[i].x + v[i].y) + (v[i].z + v[i].w);
  }
  #pragma unroll
  for (int o = 32; o > 0; o >>= 1) sum += __shfl_xor(sum, o, 64);
  if ((t & 63) == 0) red[t >> 6] = sum;
  __syncthreads();
  const float inv = 1.f / (red[0] + red[1] + red[2] + red[3]);

  #pragma unroll
  for (int i = 0; i < 4; ++i) {
    f16x4 o4 = {(f16)(v[i].x * inv), (f16)(v[i].y * inv),
                (f16)(v[i].z * inv), (f16)(v[i].w * inv)};
    *(f16x4*)(p + i * 1024 + t * 4) = o4;
  }
}

// ---------------------------------------------------------------------------
__global__ __launch_bounds__(256) void cvt_f32_f16(
    const float* __restrict__ src, f16* __restrict__ dst, long long n)
{
  long long i = ((long long)blockIdx.x * 256 + threadIdx.x) * 4;
  if (i >= n) return;
  float4 v = *(const float4*)(src + i);
  f16x4 o = {(f16)v.x, (f16)v.y, (f16)v.z, (f16)v.w};
  *(f16x4*)(dst + i) = o;
}

// ---------------------------------------------------------------------------
extern "C" void kernel_launch(void* const* d_in, const int* in_sizes, int n_in,
                              void* d_out, int out_size, void* d_ws, size_t ws_size,
                              hipStream_t stream)
{
  const float* x  = (const float*)d_in[0];
  const float* Wq = (const float*)d_in[1];
  const float* Wk = (const float*)d_in[2];
  const float* Wv = (const float*)d_in[3];
  float* out = (float*)d_out;

  const int Bn = 8, T = 4096, Cd = 1024, Hd = 1024;
  const long long BT = (long long)Bn * T;        // 32768

  char* ws = (char*)d_ws;
  const size_t MB = 1u << 20;
  // layout: [xb 64MiB | w 6MiB | qb 64MiB | kb 64MiB | vT 64MiB | P ...]
  // S (fp32, 64MiB, per-batch reuse) aliases xb — xb is dead after projections.
  f16*   xb  = (f16*)ws;
  float* S   = (float*)ws;
  f16*   wqb = (f16*)(ws + 64 * MB);
  f16*   wkb = wqb + (size_t)Hd * Cd;
  f16*   wvb = wkb + (size_t)Hd * Cd;
  f16*   qb  = (f16*)(ws + 70 * MB);
  f16*   kb  = qb + (size_t)BT * Hd;
  f16*   vT  = kb + (size_t)BT * Hd;             // [b][h][t]
  f16*   P   = vT + (size_t)BT * Hd;

  const size_t need_small = 70 * MB + 3 * (size_t)BT * Hd * 2 + (size_t)T * T * 2;
  const size_t need_big   = 70 * MB + 3 * (size_t)BT * Hd * 2 + (size_t)Bn * T * T * 2;
  if (ws_size < need_small) return;              // can't run — fail cleanly
  const bool bigP = ws_size >= need_big;

  // 1) fp32 -> f16 converts
  cvt_f32_f16<<<dim3((unsigned)(BT * Cd / 1024)), 256, 0, stream>>>(x, xb, BT * Cd);
  cvt_f32_f16<<<dim3(1024), 256, 0, stream>>>(Wq, wqb, (long long)Hd * Cd);
  cvt_f32_f16<<<dim3(1024), 256, 0, stream>>>(Wk, wkb, (long long)Hd * Cd);
  cvt_f32_f16<<<dim3(1024), 256, 0, stream>>>(Wv, wvb, (long long)Hd * Cd);

  // 2) q = x Wq^T, k = x Wk^T (z-batched: wkb/kb adjacent to wqb/qb)
  gemm_bt<f16><<<dim3(Hd / 128, (unsigned)(BT / 128), 2), 256, 0, stream>>>(
      xb, wqb, qb, Cd, Cd, Cd, Hd,
      0LL, (long long)Hd * Cd, (long long)BT * Hd, 1.0f);

  // 3) vT_b[h][t] = sum_c Wv[h][c] x_b[t][c]  (bt-GEMM, z over batches)
  gemm_bt<f16><<<dim3(T / 128, Hd / 128, Bn), 256, 0, stream>>>(
      wvb, xb, vT, Cd, Cd, Cd, T,
      0LL, (long long)T * Cd, (long long)Hd * T, 1.0f);

  // 4) per batch: S = (q_b k_b^T)/sqrt(C), softmax -> P_b
  for (int b = 0; b < Bn; ++b) {
    f16* Pb = bigP ? P + (size_t)b * T * T : P;
    gemm_bt<float><<<dim3(T / 128, T / 128, 1), 256, 0, stream>>>(
        qb + (size_t)b * T * Hd, kb + (size_t)b * T * Hd, S,
        Hd, Hd, Hd, T, 0LL, 0LL, 0LL, 0.03125f);
    softmax_rows<<<dim3(T), 256, 0, stream>>>(S, Pb, T);
    if (!bigP) {  // low-ws fallback: PV per batch
      gemm_bt<float><<<dim3(Hd / 128, T / 128, 1), 256, 0, stream>>>(
          Pb, vT + (size_t)b * Hd * T, out + (size_t)b * T * Hd,
          T, T, T, Hd, 0LL, 0LL, 0LL, 1.0f);
    }
  }

  // 5) out_b = P_b vT_b^T, all batches in one launch (2048 blocks)
  if (bigP) {
    gemm_bt<float><<<dim3(Hd / 128, T / 128, Bn), 256, 0, stream>>>(
        P, vT, out, T, T, T, Hd,
        (long long)T * T, (long long)Hd * T, (long long)T * Hd, 1.0f);
  }
  (void)in_sizes; (void)n_in; (void)out_size;
}

// Round 2
// 1970.641 us; speedup vs baseline: 1.0317x; 1.0317x over previous
//
#include <hip/hip_runtime.h>

typedef _Float16 f16;
typedef _Float16 f16x8 __attribute__((ext_vector_type(8)));
typedef _Float16 f16x4 __attribute__((ext_vector_type(4)));
typedef float f32x4 __attribute__((ext_vector_type(4)));

// ---------------------------------------------------------------------------
// async 16B global -> LDS copy (global_load_lds_dwordx4)
// NOTE: LDS dest is wave-uniform base + lane*16; our layouts respect that.
// ---------------------------------------------------------------------------
__device__ __forceinline__ void gload_lds16(const void* g, void* l) {
  __builtin_amdgcn_global_load_lds(
      (const __attribute__((address_space(1))) unsigned int*)g,
      (__attribute__((address_space(3))) unsigned int*)l,
      16, 0, 0);
}

// ---------------------------------------------------------------------------
// C = scale * A * B^T  (A: M x K row-major, B: N x K row-major, C: M x N)
// m97 structure: 128x128 tile, BK=32, 256 thr = 4 waves in 2x2, each wave
// 64x64 via 4x4 grid of 16x16x32 f16 MFMAs. All dims multiples of 128/32.
// z-batched via sAz/sBz/sCz element strides.
// ---------------------------------------------------------------------------
template <typename CT>
__global__ __launch_bounds__(256) void gemm_bt(
    const f16* __restrict__ A, const f16* __restrict__ B, CT* __restrict__ C,
    int K, int lda, int ldb, int ldc,
    long long sAz, long long sBz, long long sCz, float scale)
{
  __shared__ f16 As[128 * 32];  // [m][k] row-major, 8 KiB
  __shared__ f16 Bs[128 * 32];  // [n][k] row-major

  const int t    = threadIdx.x;
  const int lane = t & 63;
  const int wave = t >> 6;
  const int wm   = wave >> 1;   // 0..1
  const int wn   = wave & 1;    // 0..1

  const long long bm = (long long)blockIdx.y * 128;
  const long long bn = (long long)blockIdx.x * 128;

  const f16* Ab = A + (long long)blockIdx.z * sAz;
  const f16* Bb = B + (long long)blockIdx.z * sBz;
  CT*        Cb = C + (long long)blockIdx.z * sCz;

  // staging: 128x32 f16 tile = 512 chunks of 16B; thread t does chunks t, t+256
  const int row0 = t >> 2;        // 0..63
  const int kp   = (t & 3) * 8;   // 0,8,16,24
  const f16* ag0 = Ab + (bm + row0)      * lda + kp;
  const f16* ag1 = Ab + (bm + row0 + 64) * lda + kp;
  const f16* bg0 = Bb + (bn + row0)      * ldb + kp;
  const f16* bg1 = Bb + (bn + row0 + 64) * ldb + kp;
  f16* al0 = As + t * 8;
  f16* al1 = As + (t + 256) * 8;
  f16* bl0 = Bs + t * 8;
  f16* bl1 = Bs + (t + 256) * 8;

  f32x4 acc[4][4];
  #pragma unroll
  for (int i = 0; i < 4; ++i)
    #pragma unroll
    for (int j = 0; j < 4; ++j)
      acc[i][j] = {0.f, 0.f, 0.f, 0.f};

  // fragment addressing: A[m=lane&15][k=(lane>>4)*8+j], B^T[k][n=lane&15]
  const int ar = wm * 64 + (lane & 15);
  const int br = wn * 64 + (lane & 15);
  const int lk = (lane >> 4) * 8;

  for (int k0 = 0; k0 < K; k0 += 32) {
    __syncthreads();               // previous tile's frag reads done
    gload_lds16(ag0 + k0, al0);
    gload_lds16(ag1 + k0, al1);
    gload_lds16(bg0 + k0, bl0);
    gload_lds16(bg1 + k0, bl1);
    __syncthreads();               // drains vmcnt -> staging complete

    f16x8 af[4], bf[4];
    #pragma unroll
    for (int mi = 0; mi < 4; ++mi)
      af[mi] = *(const f16x8*)&As[(ar + mi * 16) * 32 + lk];
    #pragma unroll
    for (int ni = 0; ni < 4; ++ni)
      bf[ni] = *(const f16x8*)&Bs[(br + ni * 16) * 32 + lk];

    #pragma unroll
    for (int mi = 0; mi < 4; ++mi)
      #pragma unroll
      for (int ni = 0; ni < 4; ++ni)
        acc[mi][ni] = __builtin_amdgcn_mfma_f32_16x16x32_f16(
            af[mi], bf[ni], acc[mi][ni], 0, 0, 0);
  }

  // epilogue: D row = (lane>>4)*4 + r, col = lane&15  (verified m89/m91)
  const long long crow = bm + wm * 64 + (lane >> 4) * 4;
  const long long ccol = bn + wn * 64 + (lane & 15);
  #pragma unroll
  for (int mi = 0; mi < 4; ++mi)
    #pragma unroll
    for (int ni = 0; ni < 4; ++ni)
      #pragma unroll
      for (int r = 0; r < 4; ++r)
        Cb[(crow + mi * 16 + r) * ldc + ccol + ni * 16] =
            (CT)(acc[mi][ni][r] * scale);
}

// ---------------------------------------------------------------------------
// row softmax, f16 in/out, IN-PLACE. One 256-thr block per row of T=4096.
// fp32 internal math; 16 elements per thread as two f16x8 vectors.
// ---------------------------------------------------------------------------
__global__ __launch_bounds__(256) void softmax_rows_f16(
    f16* __restrict__ S, int T)
{
  const size_t row = blockIdx.x;
  const int t      = threadIdx.x;
  f16* s = S + row * (size_t)T;

  f16x8 a = *(const f16x8*)(s + t * 16);
  f16x8 b = *(const f16x8*)(s + t * 16 + 8);

  float v[16];
  float mx = -3.4e38f;
  #pragma unroll
  for (int i = 0; i < 8; ++i) { v[i]     = (float)a[i]; mx = fmaxf(mx, v[i]); }
  #pragma unroll
  for (int i = 0; i < 8; ++i) { v[8 + i] = (float)b[i]; mx = fmaxf(mx, v[8 + i]); }

  __shared__ float red[4];
  #pragma unroll
  for (int o = 32; o > 0; o >>= 1) mx = fmaxf(mx, __shfl_xor(mx, o, 64));
  if ((t & 63) == 0) red[t >> 6] = mx;
  __syncthreads();
  mx = fmaxf(fmaxf(red[0], red[1]), fmaxf(red[2], red[3]));
  __syncthreads();                         // protect red reuse

  float sum = 0.f;
  #pragma unroll
  for (int i = 0; i < 16; ++i) { v[i] = __expf(v[i] - mx); sum += v[i]; }

  #pragma unroll
  for (int o = 32; o > 0; o >>= 1) sum += __shfl_xor(sum, o, 64);
  if ((t & 63) == 0) red[t >> 6] = sum;
  __syncthreads();
  const float inv = 1.f / (red[0] + red[1] + red[2] + red[3]);

  #pragma unroll
  for (int i = 0; i < 8; ++i) a[i] = (f16)(v[i] * inv);
  #pragma unroll
  for (int i = 0; i < 8; ++i) b[i] = (f16)(v[8 + i] * inv);
  *(f16x8*)(s + t * 16)     = a;
  *(f16x8*)(s + t * 16 + 8) = b;
}

// ---------------------------------------------------------------------------
__global__ __launch_bounds__(256) void cvt_f32_f16(
    const float* __restrict__ src, f16* __restrict__ dst, long long n)
{
  long long i = ((long long)blockIdx.x * 256 + threadIdx.x) * 4;
  if (i >= n) return;
  float4 v = *(const float4*)(src + i);
  f16x4 o = {(f16)v.x, (f16)v.y, (f16)v.z, (f16)v.w};
  *(f16x4*)(dst + i) = o;
}

// ---------------------------------------------------------------------------
extern "C" void kernel_launch(void* const* d_in, const int* in_sizes, int n_in,
                              void* d_out, int out_size, void* d_ws, size_t ws_size,
                              hipStream_t stream)
{
  const float* x  = (const float*)d_in[0];
  const float* Wq = (const float*)d_in[1];
  const float* Wk = (const float*)d_in[2];
  const float* Wv = (const float*)d_in[3];
  float* out = (float*)d_out;

  const int Bn = 8, T = 4096, Cd = 1024, Hd = 1024;
  const long long BT = (long long)Bn * T;        // 32768

  char* ws = (char*)d_ws;
  const size_t MB = 1u << 20;
  // layout: [xb 64MiB | w 6MiB | qb 64MiB | kb 64MiB | vT 64MiB | S(f16) 256MiB]
  // small-ws fallback: per-batch S (f16, 32MiB) aliases xb (dead after vT).
  f16*   xb  = (f16*)ws;
  f16*   wqb = (f16*)(ws + 64 * MB);
  f16*   wkb = wqb + (size_t)Hd * Cd;
  f16*   wvb = wkb + (size_t)Hd * Cd;
  f16*   qb  = (f16*)(ws + 70 * MB);
  f16*   kb  = qb + (size_t)BT * Hd;
  f16*   vT  = kb + (size_t)BT * Hd;             // [b][h][t]
  f16*   Sbig = vT + (size_t)BT * Hd;            // [b][t][t] f16

  const size_t need_small = 70 * MB + 3 * (size_t)BT * Hd * 2;
  const size_t need_big   = need_small + (size_t)Bn * T * T * 2;
  if (ws_size < need_small) return;              // can't run — fail cleanly
  const bool bigP = ws_size >= need_big;

  // 1) fp32 -> f16 converts
  cvt_f32_f16<<<dim3((unsigned)(BT * Cd / 1024)), 256, 0, stream>>>(x, xb, BT * Cd);
  cvt_f32_f16<<<dim3(1024), 256, 0, stream>>>(Wq, wqb, (long long)Hd * Cd);
  cvt_f32_f16<<<dim3(1024), 256, 0, stream>>>(Wk, wkb, (long long)Hd * Cd);
  cvt_f32_f16<<<dim3(1024), 256, 0, stream>>>(Wv, wvb, (long long)Hd * Cd);

  // 2) q = x Wq^T, k = x Wk^T (z-batched: wkb/kb adjacent to wqb/qb)
  gemm_bt<f16><<<dim3(Hd / 128, (unsigned)(BT / 128), 2), 256, 0, stream>>>(
      xb, wqb, qb, Cd, Cd, Cd, Hd,
      0LL, (long long)Hd * Cd, (long long)BT * Hd, 1.0f);

  // 3) vT_b[h][t] = sum_c Wv[h][c] x_b[t][c]  (bt-GEMM, z over batches)
  gemm_bt<f16><<<dim3(T / 128, Hd / 128, Bn), 256, 0, stream>>>(
      wvb, xb, vT, Cd, Cd, Cd, T,
      0LL, (long long)T * Cd, (long long)Hd * T, 1.0f);

  if (bigP) {
    // 4) S_b = (q_b k_b^T)/sqrt(C) as f16, ALL batches, one launch
    gemm_bt<f16><<<dim3(T / 128, T / 128, Bn), 256, 0, stream>>>(
        qb, kb, Sbig, Hd, Hd, Hd, T,
        (long long)T * Hd, (long long)T * Hd, (long long)T * T, 0.03125f);
    // 5) softmax in-place over all 32768 rows, one launch
    softmax_rows_f16<<<dim3((unsigned)(Bn * T)), 256, 0, stream>>>(Sbig, T);
    // 6) out_b = P_b vT_b^T, one launch
    gemm_bt<float><<<dim3(Hd / 128, T / 128, Bn), 256, 0, stream>>>(
        Sbig, vT, out, T, T, T, Hd,
        (long long)T * T, (long long)Hd * T, (long long)T * Hd, 1.0f);
  } else {
    // low-ws fallback: per-batch, S aliases xb (xb dead after step 3)
    f16* Sb = xb;
    for (int b = 0; b < Bn; ++b) {
      gemm_bt<f16><<<dim3(T / 128, T / 128, 1), 256, 0, stream>>>(
          qb + (size_t)b * T * Hd, kb + (size_t)b * T * Hd, Sb,
          Hd, Hd, Hd, T, 0LL, 0LL, 0LL, 0.03125f);
      softmax_rows_f16<<<dim3(T), 256, 0, stream>>>(Sb, T);
      gemm_bt<float><<<dim3(Hd / 128, T / 128, 1), 256, 0, stream>>>(
          Sb, vT + (size_t)b * Hd * T, out + (size_t)b * T * Hd,
          T, T, T, Hd, 0LL, 0LL, 0LL, 1.0f);
    }
  }
  (void)in_sizes; (void)n_in; (void)out_size;
}

// Round 3
// 1432.999 us; speedup vs baseline: 1.4188x; 1.3752x over previous
//
#include <hip/hip_runtime.h>

typedef _Float16 f16;
typedef _Float16 f16x8 __attribute__((ext_vector_type(8)));
typedef _Float16 f16x4 __attribute__((ext_vector_type(4)));
typedef float f32x4 __attribute__((ext_vector_type(4)));

// ---------------------------------------------------------------------------
// async 16B global -> LDS copy (global_load_lds_dwordx4)
// NOTE: LDS dest is wave-uniform base + lane*16; our layouts respect that.
// ---------------------------------------------------------------------------
__device__ __forceinline__ void gload_lds16(const void* g, void* l) {
  __builtin_amdgcn_global_load_lds(
      (const __attribute__((address_space(1))) unsigned int*)g,
      (__attribute__((address_space(3))) unsigned int*)l,
      16, 0, 0);
}

// ---------------------------------------------------------------------------
// C = scale * A * B^T  (A: M x K row-major, B: N x K row-major, C: M x N)
// m97 structure: 128x128 tile, BK=32, 256 thr = 4 waves in 2x2, each wave
// 64x64 via 4x4 grid of 16x16x32 f16 MFMAs. All dims multiples of 128/32.
// z-batched via sAz/sBz/sCz element strides.
// ---------------------------------------------------------------------------
template <typename CT>
__global__ __launch_bounds__(256) void gemm_bt(
    const f16* __restrict__ A, const f16* __restrict__ B, CT* __restrict__ C,
    int K, int lda, int ldb, int ldc,
    long long sAz, long long sBz, long long sCz, float scale)
{
  __shared__ f16 As[128 * 32];  // [m][k] row-major, 8 KiB
  __shared__ f16 Bs[128 * 32];  // [n][k] row-major

  const int t    = threadIdx.x;
  const int lane = t & 63;
  const int wave = t >> 6;
  const int wm   = wave >> 1;   // 0..1
  const int wn   = wave & 1;    // 0..1

  const long long bm = (long long)blockIdx.y * 128;
  const long long bn = (long long)blockIdx.x * 128;

  const f16* Ab = A + (long long)blockIdx.z * sAz;
  const f16* Bb = B + (long long)blockIdx.z * sBz;
  CT*        Cb = C + (long long)blockIdx.z * sCz;

  // staging: 128x32 f16 tile = 512 chunks of 16B; thread t does chunks t, t+256
  const int row0 = t >> 2;        // 0..63
  const int kp   = (t & 3) * 8;   // 0,8,16,24
  const f16* ag0 = Ab + (bm + row0)      * lda + kp;
  const f16* ag1 = Ab + (bm + row0 + 64) * lda + kp;
  const f16* bg0 = Bb + (bn + row0)      * ldb + kp;
  const f16* bg1 = Bb + (bn + row0 + 64) * ldb + kp;
  f16* al0 = As + t * 8;
  f16* al1 = As + (t + 256) * 8;
  f16* bl0 = Bs + t * 8;
  f16* bl1 = Bs + (t + 256) * 8;

  f32x4 acc[4][4];
  #pragma unroll
  for (int i = 0; i < 4; ++i)
    #pragma unroll
    for (int j = 0; j < 4; ++j)
      acc[i][j] = {0.f, 0.f, 0.f, 0.f};

  // fragment addressing: A[m=lane&15][k=(lane>>4)*8+j], B^T[k][n=lane&15]
  const int ar = wm * 64 + (lane & 15);
  const int br = wn * 64 + (lane & 15);
  const int lk = (lane >> 4) * 8;

  for (int k0 = 0; k0 < K; k0 += 32) {
    __syncthreads();               // previous tile's frag reads done
    gload_lds16(ag0 + k0, al0);
    gload_lds16(ag1 + k0, al1);
    gload_lds16(bg0 + k0, bl0);
    gload_lds16(bg1 + k0, bl1);
    __syncthreads();               // drains vmcnt -> staging complete

    f16x8 af[4], bf[4];
    #pragma unroll
    for (int mi = 0; mi < 4; ++mi)
      af[mi] = *(const f16x8*)&As[(ar + mi * 16) * 32 + lk];
    #pragma unroll
    for (int ni = 0; ni < 4; ++ni)
      bf[ni] = *(const f16x8*)&Bs[(br + ni * 16) * 32 + lk];

    #pragma unroll
    for (int mi = 0; mi < 4; ++mi)
      #pragma unroll
      for (int ni = 0; ni < 4; ++ni)
        acc[mi][ni] = __builtin_amdgcn_mfma_f32_16x16x32_f16(
            af[mi], bf[ni], acc[mi][ni], 0, 0, 0);
  }

  // epilogue: D row = (lane>>4)*4 + r, col = lane&15  (verified m89/m91)
  const long long crow = bm + wm * 64 + (lane >> 4) * 4;
  const long long ccol = bn + wn * 64 + (lane & 15);
  #pragma unroll
  for (int mi = 0; mi < 4; ++mi)
    #pragma unroll
    for (int ni = 0; ni < 4; ++ni)
      #pragma unroll
      for (int r = 0; r < 4; ++r)
        Cb[(crow + mi * 16 + r) * ldc + ccol + ni * 16] =
            (CT)(acc[mi][ni][r] * scale);
}

// ---------------------------------------------------------------------------
// row softmax, f16 in/out, IN-PLACE. One 256-thr block per row of T=4096.
// fp32 internal math; 16 elements per thread as two f16x8 vectors.
// ---------------------------------------------------------------------------
__global__ __launch_bounds__(256) void softmax_rows_f16(
    f16* __restrict__ S, int T)
{
  const size_t row = blockIdx.x;
  const int t      = threadIdx.x;
  f16* s = S + row * (size_t)T;

  f16x8 a = *(const f16x8*)(s + t * 16);
  f16x8 b = *(const f16x8*)(s + t * 16 + 8);

  float v[16];
  float mx = -3.4e38f;
  #pragma unroll
  for (int i = 0; i < 8; ++i) { v[i]     = (float)a[i]; mx = fmaxf(mx, v[i]); }
  #pragma unroll
  for (int i = 0; i < 8; ++i) { v[8 + i] = (float)b[i]; mx = fmaxf(mx, v[8 + i]); }

  __shared__ float red[4];
  #pragma unroll
  for (int o = 32; o > 0; o >>= 1) mx = fmaxf(mx, __shfl_xor(mx, o, 64));
  if ((t & 63) == 0) red[t >> 6] = mx;
  __syncthreads();
  mx = fmaxf(fmaxf(red[0], red[1]), fmaxf(red[2], red[3]));
  __syncthreads();                         // protect red reuse

  float sum = 0.f;
  #pragma unroll
  for (int i = 0; i < 16; ++i) { v[i] = __expf(v[i] - mx); sum += v[i]; }

  #pragma unroll
  for (int o = 32; o > 0; o >>= 1) sum += __shfl_xor(sum, o, 64);
  if ((t & 63) == 0) red[t >> 6] = sum;
  __syncthreads();
  const float inv = 1.f / (red[0] + red[1] + red[2] + red[3]);

  #pragma unroll
  for (int i = 0; i < 8; ++i) a[i] = (f16)(v[i] * inv);
  #pragma unroll
  for (int i = 0; i < 8; ++i) b[i] = (f16)(v[8 + i] * inv);
  *(f16x8*)(s + t * 16)     = a;
  *(f16x8*)(s + t * 16 + 8) = b;
}

// ---------------------------------------------------------------------------
__global__ __launch_bounds__(256) void cvt_f32_f16(
    const float* __restrict__ src, f16* __restrict__ dst, long long n)
{
  long long i = ((long long)blockIdx.x * 256 + threadIdx.x) * 4;
  if (i >= n) return;
  float4 v = *(const float4*)(src + i);
  f16x4 o = {(f16)v.x, (f16)v.y, (f16)v.z, (f16)v.w};
  *(f16x4*)(dst + i) = o;
}

// ---------------------------------------------------------------------------
// Workspace plan (ws >= ~486 MiB known from R1; need only 454 for gs=8):
//   qb  @   0      (64 MiB)  [b][t][h] f16
//   kb  @  64 MiB  (64 MiB)
//   vT  @ 128 MiB  (64 MiB)  [b][h][t] f16
//   xb  @ 192 MiB  (64 MiB)  f16  -- DEAD after projections
//   S   @ 192 MiB  (gs*32 MiB) f16 -- aliases dead xb region
//   wb  @ 192 MiB + max(64, gs*32) MiB  (6 MiB)
// ---------------------------------------------------------------------------
extern "C" void kernel_launch(void* const* d_in, const int* in_sizes, int n_in,
                              void* d_out, int out_size, void* d_ws, size_t ws_size,
                              hipStream_t stream)
{
  const float* x  = (const float*)d_in[0];
  const float* Wq = (const float*)d_in[1];
  const float* Wk = (const float*)d_in[2];
  const float* Wv = (const float*)d_in[3];
  float* out = (float*)d_out;

  const int Bn = 8, T = 4096, Cd = 1024, Hd = 1024;
  const long long BT = (long long)Bn * T;        // 32768

  char* ws = (char*)d_ws;
  const size_t MB = 1u << 20;

  // pick the largest batch-group size that fits
  int gs = 0;
  for (int g = 8; g >= 1; g >>= 1) {
    size_t smax = (size_t)(g > 2 ? g * 32 : 64) * MB;  // max(64MiB, g*32MiB)
    if (ws_size >= 192 * MB + smax + 6 * MB) { gs = g; break; }
  }
  if (gs == 0) return;  // cannot run
  const size_t sspan = (size_t)(gs > 2 ? gs * 32 : 64) * MB;

  f16* qb  = (f16*)ws;
  f16* kb  = (f16*)(ws + 64 * MB);
  f16* vT  = (f16*)(ws + 128 * MB);              // [b][h][t]
  f16* xb  = (f16*)(ws + 192 * MB);              // dead after projections
  f16* S   = (f16*)(ws + 192 * MB);              // aliases xb
  f16* wqb = (f16*)(ws + 192 * MB + sspan);
  f16* wkb = wqb + (size_t)Hd * Cd;
  f16* wvb = wkb + (size_t)Hd * Cd;

  // 1) fp32 -> f16 converts
  cvt_f32_f16<<<dim3((unsigned)(BT * Cd / 1024)), 256, 0, stream>>>(x, xb, BT * Cd);
  cvt_f32_f16<<<dim3(1024), 256, 0, stream>>>(Wq, wqb, (long long)Hd * Cd);
  cvt_f32_f16<<<dim3(1024), 256, 0, stream>>>(Wk, wkb, (long long)Hd * Cd);
  cvt_f32_f16<<<dim3(1024), 256, 0, stream>>>(Wv, wvb, (long long)Hd * Cd);

  // 2) q = x Wq^T, k = x Wk^T (z-batched: wkb/kb adjacent to wqb/qb)
  gemm_bt<f16><<<dim3(Hd / 128, (unsigned)(BT / 128), 2), 256, 0, stream>>>(
      xb, wqb, qb, Cd, Cd, Cd, Hd,
      0LL, (long long)Hd * Cd, (long long)BT * Hd, 1.0f);

  // 3) vT_b[h][t] = sum_c Wv[h][c] x_b[t][c]  (bt-GEMM, z over batches)
  gemm_bt<f16><<<dim3(T / 128, Hd / 128, Bn), 256, 0, stream>>>(
      wvb, xb, vT, Cd, Cd, Cd, T,
      0LL, (long long)T * Cd, (long long)Hd * T, 1.0f);

  // 4-6) attention in batch groups of gs (xb is dead now; S reuses its space)
  for (int b0 = 0; b0 < Bn; b0 += gs) {
    // S_b = (q_b k_b^T)/sqrt(C) as f16
    gemm_bt<f16><<<dim3(T / 128, T / 128, gs), 256, 0, stream>>>(
        qb + (size_t)b0 * T * Hd, kb + (size_t)b0 * T * Hd, S,
        Hd, Hd, Hd, T,
        (long long)T * Hd, (long long)T * Hd, (long long)T * T, 0.03125f);
    // softmax in-place
    softmax_rows_f16<<<dim3((unsigned)(gs * T)), 256, 0, stream>>>(S, T);
    // out_b = P_b vT_b^T
    gemm_bt<float><<<dim3(Hd / 128, T / 128, gs), 256, 0, stream>>>(
        S, vT + (size_t)b0 * Hd * T, out + (size_t)b0 * T * Hd,
        T, T, T, Hd,
        (long long)T * T, (long long)Hd * T, (long long)T * Hd, 1.0f);
  }
  (void)in_sizes; (void)n_in; (void)out_size;
}